// Round 9
// baseline (1044.878 us; speedup 1.0000x reference)
//
#include <hip/hip_runtime.h>
#include <stdint.h>

// ---------------------------------------------------------------------------
// MovingAverageGatedAttention (MEGA-style) forward, MI355X/gfx950.
// B=2 S=2048 D=2048 Z=512 HD=4096 H=8 N=8 ZH=64 VH=512 GROUPS=32
// Pipeline: tsn -> cema -> rms(mx) -> {z->q,k ; v=silu(tsn@wv) ; r=silu(mx@wr)}
//           -> flash attn (causal, dqk=64, dv=512) * r -> [mx|attn]@[wh1;wh2]+x
// R1: cema chunked parallel scan. R2: attn vsplit+swizzle (259us).
// R3/R4: barrier-free attn regressed (spills). Reverted.
// R5: 1 barrier/iter attn (dbuf sP/sAl) + early V-to-regs: attn 198us.
// R6: attn K-LDS prefetch + speculative-exp softmax + setprio: attn <176us.
// R7: GEMM 2-phase dbuf + wh1/wh2 K-concat fusion: 985us (best).
// R8: NEUTRAL: counted-vmcnt + sched_barrier pins (m141 mode); n-only XCD
//     swizzle regressed FETCH 139->225MB.
// R9: REGRESSED (1033): square-chunks fixed FETCH (115MB) but time-neutral
//     (HBM 8.8%, not BW-bound); 1-barrier 3-buf loop cost +48us. Lesson:
//     loop is fine; PARALLELISM is the cap (whc: 512 blocks = 2/CU, Occ 23%).
// R10: revert loop to R7-exact 2-phase. Split-K the whc GEMM 2-way
//     (gridDim.z=2, K=3072/half -> 1024 blocks = 4/CU), halves write
//     disjoint fp32 partials (dead tsn/cema regions, no atomics); part0
//     folds bias+x; add_kernel sums partials into out (~12us).
// ---------------------------------------------------------------------------

typedef __bf16 bf16_t;
typedef bf16_t bf16x8 __attribute__((ext_vector_type(8)));
typedef float floatx4 __attribute__((ext_vector_type(4)));
typedef __attribute__((address_space(1))) unsigned int as1_uint;
typedef __attribute__((address_space(3))) unsigned int as3_uint;

static constexpr int kB = 2, kS = 2048, kD = 2048;
static constexpr int kZ = 512, kHD = 4096, kH = 8;
static constexpr int kG = 32;
static constexpr int kC = 64, kL = 32;  // cema: chunks, chunk length (kC*kL==kS)

__device__ __forceinline__ void async16(void* lds, const void* g) {
  // gfx950 direct global->LDS, 16B/lane. LDS dest = wave-uniform base + lane*16.
  __builtin_amdgcn_global_load_lds((const as1_uint*)(size_t)g, (as3_uint*)lds, 16, 0, 0);
}

__device__ __forceinline__ float sigm(float x) { return 1.0f / (1.0f + expf(-x)); }

// ---------------- weight fp32 (K,N) -> bf16 (N,K) transpose ----------------
// Writes Wt[n][colOff + k] with row stride ldWt (supports K-concatenation).
__global__ __launch_bounds__(256) void wtrans_kernel(const float* __restrict__ W,
                                                     bf16_t* __restrict__ Wt,
                                                     int K, int N, int ldWt,
                                                     int colOff) {
  __shared__ float tile[32][33];
  int n0 = blockIdx.x * 32, k0 = blockIdx.y * 32;
  int tx = threadIdx.x & 31, ty = threadIdx.x >> 5;  // ty in 0..7
#pragma unroll
  for (int i = 0; i < 32; i += 8)
    tile[ty + i][tx] = W[(size_t)(k0 + ty + i) * N + n0 + tx];
  __syncthreads();
#pragma unroll
  for (int i = 0; i < 32; i += 8)
    Wt[(size_t)(n0 + ty + i) * ldWt + colOff + k0 + tx] = (bf16_t)tile[tx][ty + i];
}

// ---------------- out = a + b (fp32, vectorized) ---------------------------
__global__ __launch_bounds__(256) void add_kernel(const float* __restrict__ a,
                                                  const float* __restrict__ b,
                                                  float* __restrict__ out) {
  size_t i = ((size_t)blockIdx.x * 256 + threadIdx.x) * 4;
  float4 va = *(const float4*)(a + i);
  float4 vb = *(const float4*)(b + i);
  *(float4*)(out + i) = make_float4(va.x + vb.x, va.y + vb.y, va.z + vb.z, va.w + vb.w);
}

// ---------------- timestep norm: per-(b,s) group sums ----------------------
__global__ __launch_bounds__(256) void tsn_sums(const float* __restrict__ x,
                                                float* __restrict__ g1,
                                                float* __restrict__ g2) {
  int bs = blockIdx.x, t = threadIdx.x;
  const float4* rp = (const float4*)(x + (size_t)bs * kD + t * 8);
  float4 a = rp[0], b = rp[1];
  float s1 = a.x + a.y + a.z + a.w + b.x + b.y + b.z + b.w;
  float s2 = a.x * a.x + a.y * a.y + a.z * a.z + a.w * a.w +
             b.x * b.x + b.y * b.y + b.z * b.z + b.w * b.w;
  s1 += __shfl_xor(s1, 1); s2 += __shfl_xor(s2, 1);
  s1 += __shfl_xor(s1, 2); s2 += __shfl_xor(s2, 2);
  s1 += __shfl_xor(s1, 4); s2 += __shfl_xor(s2, 4);
  if ((t & 7) == 0) {
    int g = t >> 3, b_ = bs >> 11, s = bs & 2047;
    size_t idx = ((size_t)b_ * kG + g) * kS + s;   // [b][g][s] layout (scan-friendly)
    g1[idx] = s1; g2[idx] = s2;
  }
}

// ---------------- cumulative sum over s per (b,g) --------------------------
__global__ void tsn_scan(float* __restrict__ g1, float* __restrict__ g2) {
  int lane = threadIdx.x;  // 64 threads = 1 wave; blockIdx.x = b*32+g
  size_t base = (size_t)blockIdx.x * kS;
  float c1 = 0.f, c2 = 0.f;
  for (int c = 0; c < kS / 64; ++c) {
    size_t idx = base + c * 64 + lane;
    float v1 = g1[idx], v2 = g2[idx];
#pragma unroll
    for (int off = 1; off < 64; off <<= 1) {
      float t1 = __shfl_up(v1, off), t2 = __shfl_up(v2, off);
      if (lane >= off) { v1 += t1; v2 += t2; }
    }
    v1 += c1; v2 += c2;
    g1[idx] = v1; g2[idx] = v2;
    c1 = __shfl(v1, 63); c2 = __shfl(v2, 63);
  }
}

// ---------------- timestep norm apply (writes fp32 + bf16) -----------------
__global__ __launch_bounds__(256) void tsn_norm(const float* __restrict__ x,
    const float* __restrict__ g1, const float* __restrict__ g2,
    const float* __restrict__ w, const float* __restrict__ bias,
    float* __restrict__ tsn, bf16_t* __restrict__ tsnb) {
  int bs = blockIdx.x, t = threadIdx.x;
  int b = bs >> 11, s = bs & 2047, g = t >> 3;
  float cnt = (float)(s + 1) * 64.0f;
  size_t gidx = ((size_t)b * kG + g) * kS + s;
  float mean = g1[gidx] / cnt;
  float inv = rsqrtf(g2[gidx] / cnt - mean * mean + 1e-5f);
  size_t base = (size_t)bs * kD + t * 8;
  float4 a = ((const float4*)(x + base))[0];
  float4 c = ((const float4*)(x + base))[1];
  float v[8] = {a.x, a.y, a.z, a.w, c.x, c.y, c.z, c.w};
  float4 w0 = ((const float4*)(w + t * 8))[0], w1 = ((const float4*)(w + t * 8))[1];
  float4 b0 = ((const float4*)(bias + t * 8))[0], b1 = ((const float4*)(bias + t * 8))[1];
  float wv[8] = {w0.x, w0.y, w0.z, w0.w, w1.x, w1.y, w1.z, w1.w};
  float bv[8] = {b0.x, b0.y, b0.z, b0.w, b1.x, b1.y, b1.z, b1.w};
  float r[8];
  bf16x8 ob;
#pragma unroll
  for (int i = 0; i < 8; ++i) {
    r[i] = (v[i] - mean) * inv * wv[i] + bv[i];
    ob[i] = (bf16_t)r[i];
  }
  ((float4*)(tsn + base))[0] = make_float4(r[0], r[1], r[2], r[3]);
  ((float4*)(tsn + base))[1] = make_float4(r[4], r[5], r[6], r[7]);
  *(bf16x8*)(tsnb + base) = ob;
}

// ---------------- complex EMA, chunked parallel scan -----------------------
__device__ __forceinline__ void cema_coeffs(const float* __restrict__ alpha,
    const float* __restrict__ delta, float st, int d,
    float (&qr)[8], float (&qi)[8], float (&ur)[8], float (&ui)[8]) {
  const float4* ap = (const float4*)(alpha + (size_t)d * 8);
  const float4* dp = (const float4*)(delta + (size_t)d * 8);
  float4 a0 = ap[0], a1 = ap[1], d0 = dp[0], d1 = dp[1];
  float av[8] = {a0.x, a0.y, a0.z, a0.w, a1.x, a1.y, a1.z, a1.w};
  float dv[8] = {d0.x, d0.y, d0.z, d0.w, d1.x, d1.y, d1.z, d1.w};
#pragma unroll
  for (int n = 0; n < 8; ++n) {
    float p = sigm(av[n]);
    float qm = 1.0f - p * sigm(dv[n]);
    float ph = st * (0.78539816339744831f * (float)(n + 1));  // 2*pi*(n+1)/8
    float cs = cosf(ph), sn = sinf(ph);
    qr[n] = qm * cs; qi[n] = qm * sn;
    ur[n] = p * cs;  ui[n] = p * sn;
  }
}

__global__ __launch_bounds__(256) void cema_pass1(const float* __restrict__ tsn,
    const float* __restrict__ alpha, const float* __restrict__ delta,
    const float* __restrict__ theta, float2* __restrict__ hend) {
  int b = blockIdx.x >> 6, c = blockIdx.x & 63;
  int d = blockIdx.y * 256 + threadIdx.x;
  float st = sigm(theta[d]);
  float qr[8], qi[8], ur[8], ui[8];
  cema_coeffs(alpha, delta, st, d, qr, qi, ur, ui);
  float hr[8] = {0}, hi[8] = {0};
  const float* xp = tsn + ((size_t)b * kS + c * kL) * kD + d;
  for (int i = 0; i < kL; ++i) {
    float xt = xp[(size_t)i * kD];
#pragma unroll
    for (int n = 0; n < 8; ++n) {
      float tr = fmaf(qr[n], hr[n], fmaf(-qi[n], hi[n], ur[n] * xt));
      float ti = fmaf(qi[n], hr[n], fmaf(qr[n], hi[n], ui[n] * xt));
      hr[n] = tr; hi[n] = ti;
    }
  }
  float2* op = hend + (((size_t)(b * kC + c)) * kD + d) * 8;
#pragma unroll
  for (int n = 0; n < 8; ++n) op[n] = make_float2(hr[n], hi[n]);
}

__global__ __launch_bounds__(256) void cema_pass2(const float2* __restrict__ hend,
    const float* __restrict__ alpha, const float* __restrict__ delta,
    const float* __restrict__ theta, float2* __restrict__ hinit) {
  int tid = blockIdx.x * 256 + threadIdx.x;  // b*D*8 + d*8 + n
  int n = tid & 7, d = (tid >> 3) & 2047, b = tid >> 14;
  int dn = d * 8 + n;
  float p = sigm(alpha[dn]);
  float qm = 1.0f - p * sigm(delta[dn]);
  float ph = sigm(theta[d]) * (0.78539816339744831f * (float)(n + 1));
  float ar = qm * cosf(ph), ai = qm * sinf(ph);
#pragma unroll
  for (int t = 0; t < 5; ++t) {
    float nr = ar * ar - ai * ai;
    ai = 2.0f * ar * ai;
    ar = nr;
  }
  float hr = 0.f, hi = 0.f;
  for (int c = 0; c < kC; ++c) {
    size_t idx = (((size_t)(b * kC + c)) * kD + d) * 8 + n;
    hinit[idx] = make_float2(hr, hi);
    float2 e = hend[idx];
    float nr = fmaf(ar, hr, fmaf(-ai, hi, e.x));
    float ni = fmaf(ai, hr, fmaf(ar, hi, e.y));
    hr = nr; hi = ni;
  }
}

__global__ __launch_bounds__(256) void cema_pass3(const float* __restrict__ tsn,
    const float* __restrict__ alpha, const float* __restrict__ delta,
    const float* __restrict__ theta, const float* __restrict__ gamma,
    const float* __restrict__ omega, const float2* __restrict__ hinit,
    float* __restrict__ outc) {
  int b = blockIdx.x >> 6, c = blockIdx.x & 63;
  int d = blockIdx.y * 256 + threadIdx.x;
  float st = sigm(theta[d]);
  float qr[8], qi[8], ur[8], ui[8];
  cema_coeffs(alpha, delta, st, d, qr, qi, ur, ui);
  float gr[8], gi[8];
  const float4* gp = (const float4*)(gamma + (size_t)d * 16);
#pragma unroll
  for (int m = 0; m < 4; ++m) {
    float4 g = gp[m];
    gr[m * 2] = g.x; gi[m * 2] = g.y; gr[m * 2 + 1] = g.z; gi[m * 2 + 1] = g.w;
  }
  float om = omega[d];
  float hr[8], hi[8];
  const float2* ip = hinit + (((size_t)(b * kC + c)) * kD + d) * 8;
#pragma unroll
  for (int n = 0; n < 8; ++n) { float2 h = ip[n]; hr[n] = h.x; hi[n] = h.y; }
  const float* xp = tsn + ((size_t)b * kS + c * kL) * kD + d;
  float* op = outc + ((size_t)b * kS + c * kL) * kD + d;
  for (int i = 0; i < kL; ++i) {
    float xt = xp[(size_t)i * kD];
    float y = 0.f;
#pragma unroll
    for (int n = 0; n < 8; ++n) {
      float tr = fmaf(qr[n], hr[n], fmaf(-qi[n], hi[n], ur[n] * xt));
      float ti = fmaf(qi[n], hr[n], fmaf(qr[n], hi[n], ui[n] * xt));
      hr[n] = tr; hi[n] = ti;
      y = fmaf(tr, gr[n], fmaf(ti, gi[n], y));
    }
    op[(size_t)i * kD] = fmaf(xt, om, y);
  }
}

// ---------------- rmsnorm over D -> bf16 mx --------------------------------
__global__ __launch_bounds__(256) void rms_kernel(const float* __restrict__ in,
                                                  const float* __restrict__ w,
                                                  bf16_t* __restrict__ outb) {
  int bs = blockIdx.x, t = threadIdx.x;
  size_t base = (size_t)bs * kD + t * 8;
  float4 a = ((const float4*)(in + base))[0];
  float4 c = ((const float4*)(in + base))[1];
  float v[8] = {a.x, a.y, a.z, a.w, c.x, c.y, c.z, c.w};
  float ss = 0.f;
#pragma unroll
  for (int i = 0; i < 8; ++i) ss += v[i] * v[i];
#pragma unroll
  for (int off = 1; off < 64; off <<= 1) ss += __shfl_xor(ss, off);
  __shared__ float red[4];
  if ((t & 63) == 0) red[t >> 6] = ss;
  __syncthreads();
  ss = red[0] + red[1] + red[2] + red[3];
  float inv = rsqrtf(ss * (1.0f / 2048.0f) + 1e-5f);
  float4 w0 = ((const float4*)(w + t * 8))[0], w1 = ((const float4*)(w + t * 8))[1];
  float wv[8] = {w0.x, w0.y, w0.z, w0.w, w1.x, w1.y, w1.z, w1.w};
  bf16x8 ob;
#pragma unroll
  for (int i = 0; i < 8; ++i) ob[i] = (bf16_t)(v[i] * inv * wv[i]);
  *(bf16x8*)(outb + base) = ob;
}

// ---------------- z -> per-head rms -> gamma/beta -> rotary -> q,k bf16 ----
// q,k layout: [B][H][S][64]
__global__ __launch_bounds__(256) void zpost_kernel(const float* __restrict__ z,
    const float* __restrict__ ag, const float* __restrict__ ab,
    const float* __restrict__ freqs, bf16_t* __restrict__ q, bf16_t* __restrict__ k) {
  int bs = blockIdx.x, t = threadIdx.x;
  int b = bs >> 11, s = bs & 2047;
  int h = t >> 5, i = t & 31;  // head, rotary pair
  const float* zr = z + (size_t)bs * kZ + h * 64;
  float re = zr[2 * i], im = zr[2 * i + 1];
  float ss = re * re + im * im;
#pragma unroll
  for (int off = 1; off < 32; off <<= 1) ss += __shfl_xor(ss, off);
  float inv = rsqrtf(ss * (1.0f / 64.0f) + 1e-5f);
  float zne = re * inv, zno = im * inv;
  const float rs = 0.125f;  // 1/sqrt(64)
  int ze = h * 64 + 2 * i, zo = ze + 1;
  float qe = zne * ((ag[ze] + 1.f) * rs) + ab[ze];
  float qo = zno * ((ag[zo] + 1.f) * rs) + ab[zo];
  float ke = zne * ((ag[kZ + ze] + 1.f) * rs) + ab[kZ + ze];
  float ko = zno * ((ag[kZ + zo] + 1.f) * rs) + ab[kZ + zo];
  float cs = freqs[((size_t)s * 32 + i) * 2 + 0];
  float sn = freqs[((size_t)s * 32 + i) * 2 + 1];
  size_t o = (((size_t)b * kH + h) * kS + s) * 64 + 2 * i;
  q[o]     = (bf16_t)(qe * cs - qo * sn);
  q[o + 1] = (bf16_t)(qe * sn + qo * cs);
  k[o]     = (bf16_t)(ke * cs - ko * sn);
  k[o + 1] = (bf16_t)(ke * sn + ko * cs);
}

// ---------------- bf16 MFMA GEMM: C[M,N] = A[M,K] @ Bt[N,K]^T --------------
// R7 loop (verified best): 128x128 tile, BK=32, double-buffered sA/sB, ONE
// __syncthreads per K-step; STAGE(t+1) issued before ds_read/MFMA of tile t.
// R10: optional split-K via gridDim.z: part z covers K columns
// [z*Kpart, (z+1)*Kpart). A source switches (A1,lda1)->(A2,lda2) at col K1.
// epi: 0 = +bias -> f32 ; 1 = silu(+bias) -> bf16 transposed vT[b][hd][s]
//      2 = silu(+bias) -> bf16 row-major ; 3 = +bias + add1 -> f32
//      4 = split-K partial: part0 -> outF (+bias+add1), part1 -> outF2 (raw)
__global__ __launch_bounds__(256) void gemm_bt(const bf16_t* __restrict__ A1,
    int lda1, const bf16_t* __restrict__ A2, int lda2, int K1,
    const bf16_t* __restrict__ Bt, int M, int N, int K, int Kpart,
    const float* __restrict__ bias, const float* __restrict__ add1,
    float* __restrict__ outF, float* __restrict__ outF2,
    bf16_t* __restrict__ outB, int epi) {
  __shared__ __align__(16) bf16_t sA[2][128 * 32];
  __shared__ __align__(16) bf16_t sB[2][128 * 32];
  const int t = threadIdx.x;
  const int wave = t >> 6, lane = t & 63;
  const int quad = lane >> 4, l16 = lane & 15;
  const int m0 = blockIdx.x * 128, n0 = blockIdx.y * 128;
  const int kbeg = blockIdx.z * Kpart;
  const int wm = (wave >> 1) * 64, wn = (wave & 1) * 64;

  floatx4 acc[4][4];
#pragma unroll
  for (int i = 0; i < 4; ++i)
#pragma unroll
    for (int j = 0; j < 4; ++j) acc[i][j] = (floatx4){0.f, 0.f, 0.f, 0.f};

  const int seg0 = wave * 64 + lane;        // segs 0..255
  const int seg1 = 256 + wave * 64 + lane;  // segs 256..511
  const int r0 = seg0 >> 2, c0 = (seg0 & 3) * 8;
  const int r1 = seg1 >> 2, c1 = (seg1 & 3) * 8;

  auto stage = [&](int buf, int kt) {  // kt is GLOBAL K column
    const bf16_t* Ab; int ldab; int kk;
    if (kt < K1) { Ab = A1; ldab = lda1; kk = kt; }
    else         { Ab = A2; ldab = lda2; kk = kt - K1; }
    async16(sA[buf] + (size_t)(wave * 64) * 8,       Ab + (size_t)(m0 + r0) * ldab + kk + c0);
    async16(sA[buf] + (size_t)(256 + wave * 64) * 8, Ab + (size_t)(m0 + r1) * ldab + kk + c1);
    async16(sB[buf] + (size_t)(wave * 64) * 8,       Bt + (size_t)(n0 + r0) * K + kt + c0);
    async16(sB[buf] + (size_t)(256 + wave * 64) * 8, Bt + (size_t)(n0 + r1) * K + kt + c1);
  };

  stage(0, kbeg);
  __syncthreads();  // drains vmcnt: buf0 ready

  const int nsteps = Kpart >> 5;
  for (int st = 0; st < nsteps; ++st) {
    const int cur = st & 1;
    // prefetch next tile into the other buffer (safe: all reads of that
    // buffer finished before the barrier we all just passed)
    if (st + 1 < nsteps) stage(cur ^ 1, kbeg + ((st + 1) << 5));

    bf16x8 af[4], bfr[4];
#pragma unroll
    for (int i = 0; i < 4; ++i)
      af[i] = *(const bf16x8*)(sA[cur] + (wm + i * 16 + l16) * 32 + quad * 8);
#pragma unroll
    for (int j = 0; j < 4; ++j)
      bfr[j] = *(const bf16x8*)(sB[cur] + (wn + j * 16 + l16) * 32 + quad * 8);
#pragma unroll
    for (int i = 0; i < 4; ++i)
#pragma unroll
      for (int j = 0; j < 4; ++j)
        acc[i][j] = __builtin_amdgcn_mfma_f32_16x16x32_bf16(af[i], bfr[j], acc[i][j], 0, 0, 0);

    __syncthreads();  // single barrier: drains stage(t+1); protects buffers
  }

  // epilogue: C/D layout col=l16, row=quad*4+reg
#pragma unroll
  for (int i = 0; i < 4; ++i) {
#pragma unroll
    for (int j = 0; j < 4; ++j) {
#pragma unroll
      for (int r = 0; r < 4; ++r) {
        int row = m0 + wm + i * 16 + quad * 4 + r;
        int col = n0 + wn + j * 16 + l16;
        size_t idx = (size_t)row * N + col;
        float v = acc[i][j][r];
        if (epi == 0) {
          outF[idx] = v + bias[col];
        } else if (epi == 1) {
          v += bias[col];
          v = v / (1.f + __expf(-v));
          // vT[b][hd][s] : hd = col (0..4095), b = row>>11, s = row&2047
          size_t vidx = ((size_t)(row >> 11) * kHD + col) * (size_t)kS + (row & 2047);
          outB[vidx] = (bf16_t)v;
        } else if (epi == 2) {
          v += bias[col];
          v = v / (1.f + __expf(-v));
          outB[idx] = (bf16_t)v;
        } else if (epi == 3) {
          outF[idx] = v + bias[col] + add1[idx];
        } else {  // epi == 4: split-K partial
          if (blockIdx.z == 0) {
            outF[idx] = v + bias[col] + add1[idx];
          } else {
            outF2[idx] = v;
          }
        }
      }
    }
  }
}

// ---------------- flash attention (causal) + r-gating ----------------------
// R6 structure (verified). flat grid 1024 = 32 qt-levels (desc) x 16 bh x 2 vs.
// ONE barrier per kt-iteration; sP/sAl dbuf; K tiles dbuf in LDS via
// pre-swizzled global_load_lds; speculative-exp softmax; setprio on PV.
__global__ __launch_bounds__(256) void attn_kernel(const bf16_t* __restrict__ qg,
    const bf16_t* __restrict__ kg, const bf16_t* __restrict__ vT,
    const bf16_t* __restrict__ rg, bf16_t* __restrict__ attnG) {
  const int bid = blockIdx.x;
  const int qt = (kS / 64 - 1) - (bid >> 5);  // longest-first dispatch
  const int bh = (bid >> 1) & 15;
  const int vs = bid & 1;
  const int b = bh >> 3, h = bh & 7;
  const int t = threadIdx.x;
  const int w = t >> 6, lane = t & 63;
  const int quad = lane >> 4, l16 = lane & 15;
  const int q0 = qt * 64;

  __shared__ __align__(16) bf16_t sP[2][64 * 64];  // double-buffered P
  __shared__ __align__(16) bf16_t sK[2][64 * 64];  // double-buffered K tiles
  __shared__ float sM[64], sL[64], sAl[2][64];     // m/l + dbuf rescale
  if (t < 64) { sM[t] = 0.f; sL[t] = 0.f; }        // m init 0 (scores ~|1|)

  const bf16_t* qbase = qg + ((size_t)bh * kS + q0) * 64;
  const bf16_t* kbase = kg + (size_t)bh * kS * 64;
  const bf16_t* vbase = vT + ((size_t)bh * 512 + vs * 256 + w * 64) * kS;

  // stage K tile [k0..k0+63][0..63] into dstbuf, source pre-swizzled so that
  // LDS[row*64 + cc*8 ..] holds K[row][ (cc^(row&7))*8 .. ] (cc = 16B chunk).
  auto stage_k = [&](bf16_t* dstbuf, int k0) {
#pragma unroll
    for (int half = 0; half < 2; ++half) {
      int seg = half * 256 + w * 64 + lane;   // 0..511, 16B each
      int r = seg >> 3, cc = seg & 7;
      async16(dstbuf + (size_t)(half * 256 + w * 64) * 8,
              kbase + (size_t)(k0 + r) * 64 + (cc ^ (r & 7)) * 8);
    }
  };

  bf16x8 qfrag[2];
#pragma unroll
  for (int ks = 0; ks < 2; ++ks)
    qfrag[ks] = *(const bf16x8*)(qbase + (size_t)(w * 16 + l16) * 64 + ks * 32 + quad * 8);

  floatx4 oacc[4][4];  // [mi(16 q-rows)][nj(16 v-dims)]
#pragma unroll
  for (int i = 0; i < 4; ++i)
#pragma unroll
    for (int j = 0; j < 4; ++j) oacc[i][j] = (floatx4){0.f, 0.f, 0.f, 0.f};

  stage_k(sK[0], 0);   // prologue: K tile 0
  __syncthreads();     // drains vmcnt (K0 + qfrag) ; publishes sM/sL init

  for (int kt = 0; kt <= qt; ++kt) {
    const int k0 = kt * 64;
    const int pb = kt & 1;

    if (kt < qt) stage_k(sK[pb ^ 1], k0 + 64);  // prefetch next K tile

    // ---- early V issue: this wave's 64 v-dims for tile kt (to registers).
    bf16x8 vf[2][4];
#pragma unroll
    for (int ks = 0; ks < 2; ++ks)
#pragma unroll
      for (int nj = 0; nj < 4; ++nj)
        vf[ks][nj] = *(const bf16x8*)(vbase + (size_t)(nj * 16 + l16) * kS + k0 + ks * 32 + quad * 8);

    // ---- QK^T for this wave's 16 q-rows, K from swizzled LDS -------------
    floatx4 sacc[4];
#pragma unroll
    for (int nt = 0; nt < 4; ++nt) sacc[nt] = (floatx4){0.f, 0.f, 0.f, 0.f};
#pragma unroll
    for (int ks = 0; ks < 2; ++ks)
#pragma unroll
      for (int nt = 0; nt < 4; ++nt) {
        int row = nt * 16 + l16;
        int ch = (ks * 4 + quad) ^ (row & 7);
        bf16x8 kf = *(const bf16x8*)(sK[pb] + row * 64 + ch * 8);
        sacc[nt] = __builtin_amdgcn_mfma_f32_16x16x32_bf16(qfrag[ks], kf, sacc[nt], 0, 0, 0);
      }
    if (kt == qt) {  // causal mask on diagonal tile
#pragma unroll
      for (int nt = 0; nt < 4; ++nt)
#pragma unroll
        for (int r = 0; r < 4; ++r) {
          int sk = k0 + nt * 16 + l16;
          int qq = q0 + w * 16 + quad * 4 + r;
          if (sk > qq) sacc[nt][r] = -1e30f;
        }
    }

    // ---- speculative-exp online softmax ---------------------------------
    float mo[4], mloc[4], lspec[4];
#pragma unroll
    for (int r = 0; r < 4; ++r) {
      mo[r] = sM[w * 16 + quad * 4 + r];  // same-wave owned
      mloc[r] = fmaxf(fmaxf(sacc[0][r], sacc[1][r]), fmaxf(sacc[2][r], sacc[3][r]));
    }
#pragma unroll
    for (int r = 0; r < 4; ++r) {
      float s = 0.f;
#pragma unroll
      for (int nt = 0; nt < 4; ++nt) {
        float e = __expf(sacc[nt][r] - mo[r]);
        sacc[nt][r] = e;
        s += e;
      }
      lspec[r] = s;
    }
#pragma unroll
    for (int off = 1; off < 16; off <<= 1)
#pragma unroll
      for (int r = 0; r < 4; ++r) {
        mloc[r] = fmaxf(mloc[r], __shfl_xor(mloc[r], off));
        lspec[r] += __shfl_xor(lspec[r], off);
      }
    float mnew[4], al[4];
#pragma unroll
    for (int r = 0; r < 4; ++r) {
      mnew[r] = fmaxf(mo[r], mloc[r]);
      al[r] = __expf(mo[r] - mnew[r]);
    }
    if (l16 == 0) {
#pragma unroll
      for (int r = 0; r < 4; ++r) {
        int row = w * 16 + quad * 4 + r;
        sM[row] = mnew[r];
        sL[row] = al[r] * (sL[row] + lspec[r]);
        sAl[pb][row] = al[r];
      }
    }
#pragma unroll
    for (int nt = 0; nt < 4; ++nt)
#pragma unroll
      for (int r = 0; r < 4; ++r) {
        int row = w * 16 + quad * 4 + r;
        sP[pb][row * 64 + ((nt * 16 + l16) ^ ((row & 7) << 3))] = (bf16_t)(sacc[nt][r] * al[r]);
      }

    __syncthreads();  // single barrier: P/sAl visible; vf + K-prefetch drained

    // ---- rescale O then accumulate P @ V (vf already in registers) ------
#pragma unroll
    for (int mi = 0; mi < 4; ++mi)
#pragma unroll
      for (int r = 0; r < 4; ++r) {
        float a = sAl[pb][mi * 16 + quad * 4 + r];
#pragma unroll
        for (int nj = 0; nj < 4; ++nj) oacc[mi][nj][r] *= a;
      }
    __builtin_amdgcn_s_setprio(1);
#pragma unroll
    for (int ks = 0; ks < 2; ++ks) {
      bf16x8 pa[4];
#pragma unroll
      for (int mi = 0; mi < 4; ++mi) {
        int row = mi * 16 + l16;
        pa[mi] = *(const bf16x8*)(sP[pb] + row * 64 + ((ks * 32 + quad * 8) ^ ((row & 7) << 3)));
      }
#pragma unroll
      for (int nj = 0; nj < 4; ++nj)
#pragma unroll
        for (int mi = 0; mi < 4; ++mi)
          oacc[mi][nj] = __builtin_amdgcn_mfma_f32_16x16x32_bf16(pa[mi], vf[ks][nj], oacc[mi][nj], 0, 0, 0);
    }
    __builtin_amdgcn_s_setprio(0);
  }

  // epilogue: O/l * r -> attnG bf16
#pragma unroll
  for (int mi = 0; mi < 4; ++mi)
#pragma unroll
    for (int r = 0; r < 4; ++r) {
      int srow = q0 + mi * 16 + quad * 4 + r;
      float linv = 1.0f / sL[mi * 16 + quad * 4 + r];
#pragma unroll
      for (int nj = 0; nj < 4; ++nj) {
        int hd = h * 512 + vs * 256 + w * 64 + nj * 16 + l16;
        size_t idx = ((size_t)b * kS + srow) * kHD + hd;
        float rv = (float)rg[idx];
        attnG[idx] = (bf16_t)(oacc[mi][nj][r] * linv * rv);
      }
    }
}

// ---------------------------------------------------------------------------
extern "C" void kernel_launch(void* const* d_in, const int* in_sizes, int n_in,
                              void* d_out, int out_size, void* d_ws, size_t ws_size,
                              hipStream_t stream) {
  const float* x      = (const float*)d_in[0];
  const float* tnw    = (const float*)d_in[1];
  const float* tnb    = (const float*)d_in[2];
  const float* ealpha = (const float*)d_in[3];
  const float* edelta = (const float*)d_in[4];
  const float* etheta = (const float*)d_in[5];
  const float* egamma = (const float*)d_in[6];
  const float* eomega = (const float*)d_in[7];
  const float* rmsw   = (const float*)d_in[8];
  const float* wz_w   = (const float*)d_in[9];
  const float* wz_b   = (const float*)d_in[10];
  const float* wv_w   = (const float*)d_in[11];
  const float* wv_b   = (const float*)d_in[12];
  const float* wr_w   = (const float*)d_in[13];
  const float* wr_b   = (const float*)d_in[14];
  const float* wh1_w  = (const float*)d_in[15];
  const float* wh1_b  = (const float*)d_in[16];
  const float* wh2_w  = (const float*)d_in[17];
  const float* ag     = (const float*)d_in[18];
  const float* ab     = (const float*)d_in[19];
  const float* freqs  = (const float*)d_in[20];
  float* out = (float*)d_out;

  char* ws = (char*)d_ws;
  size_t off = 0;
  auto alloc = [&](size_t bytes) -> void* {
    void* p = ws + off;
    off += (bytes + 255) & ~(size_t)255;
    return p;
  };
  // buf1: tsn fp32, later reused as vT bf16 (dead after attn -> whc partial 0)
  float*  tsn  = (float*)alloc(8388608ull * 4);
  bf16_t* tsnb = (bf16_t*)alloc(8388608ull * 2);
  float*  g1   = (float*)alloc(131072ull * 4);
  float*  g2   = (float*)alloc(131072ull * 4);
  // buf2: cema fp32 (dead after rms -> whc partial 1)
  float*  cema = (float*)alloc(8388608ull * 4);
  bf16_t* mx   = (bf16_t*)alloc(8388608ull * 2);
  bf16_t* wzT  = (bf16_t*)alloc(1048576ull * 2);
  bf16_t* wvT  = (bf16_t*)alloc(8388608ull * 2);
  bf16_t* wrT  = (bf16_t*)alloc(8388608ull * 2);
  bf16_t* whcT = (bf16_t*)alloc(12582912ull * 2);  // [2048][6144] = wh1|wh2 cat
  float*  zbuf = (float*)alloc(2097152ull * 4);
  bf16_t* qb   = (bf16_t*)alloc(2097152ull * 2);
  bf16_t* kb   = (bf16_t*)alloc(2097152ull * 2);
  bf16_t* rb   = (bf16_t*)alloc(16777216ull * 2);
  bf16_t* aG   = (bf16_t*)alloc(16777216ull * 2);
  bf16_t* vTb  = (bf16_t*)tsn;   // alias buf1 (16.8M bf16 fits in 33.5MB)
  // cema scratch: aliases rb/aG — lifetimes disjoint (cema ends before r/attn)
  float2* hend  = (float2*)rb;   // B*C*D*N complex = 16.8 MB (rb is 33.5 MB)
  float2* hinit = (float2*)aG;   // 16.8 MB (aG is 33.5 MB)
  // whc split-K partials: alias tsn (vTb dead after attn) and cema (dead
  // after rms). Each needs M*kD fp32 = 33.5 MB — exact fit.
  float* Pw0 = (float*)tsn;
  float* Pw1 = (float*)cema;

  // weights -> bf16, transposed to (N,K); wh1/wh2 concatenated along K
  wtrans_kernel<<<dim3(kZ / 32, kD / 32), 256, 0, stream>>>(wz_w, wzT, kD, kZ, kD, 0);
  wtrans_kernel<<<dim3(kHD / 32, kD / 32), 256, 0, stream>>>(wv_w, wvT, kD, kHD, kD, 0);
  wtrans_kernel<<<dim3(kHD / 32, kD / 32), 256, 0, stream>>>(wr_w, wrT, kD, kHD, kD, 0);
  wtrans_kernel<<<dim3(kD / 32, kD / 32), 256, 0, stream>>>(wh1_w, whcT, kD, kD, 6144, 0);
  wtrans_kernel<<<dim3(kD / 32, kHD / 32), 256, 0, stream>>>(wh2_w, whcT, kHD, kD, 6144, kD);

  // timestep norm
  tsn_sums<<<kB * kS, 256, 0, stream>>>(x, g1, g2);
  tsn_scan<<<kB * kG, 64, 0, stream>>>(g1, g2);
  tsn_norm<<<kB * kS, 256, 0, stream>>>(x, g1, g2, tnw, tnb, tsn, tsnb);

  // complex EMA + residual omega (chunked parallel scan)
  cema_pass1<<<dim3(kB * kC, kD / 256), 256, 0, stream>>>(tsn, ealpha, edelta,
                                                          etheta, hend);
  cema_pass2<<<kB * kD * 8 / 256, 256, 0, stream>>>(hend, ealpha, edelta,
                                                    etheta, hinit);
  cema_pass3<<<dim3(kB * kC, kD / 256), 256, 0, stream>>>(tsn, ealpha, edelta,
      etheta, egamma, eomega, hinit, cema);
  // mx = rmsnorm(cema) -> bf16
  rms_kernel<<<kB * kS, 256, 0, stream>>>(cema, rmsw, mx);

  const int M = kB * kS;  // 4096
  // z = mx @ wz + b
  gemm_bt<<<dim3(M / 128, kZ / 128), 256, 0, stream>>>(mx, kD, mx, kD, kD,
      wzT, M, kZ, kD, kD, wz_b, nullptr, zbuf, nullptr, nullptr, 0);
  // z -> q,k (per-head rms, gamma/beta, rotary)
  zpost_kernel<<<kB * kS, 256, 0, stream>>>(zbuf, ag, ab, freqs, qb, kb);
  // v = silu(tsn @ wv + b) -> vT[b][hd][s]   (NOTE: after cema; buf1 reuse OK)
  gemm_bt<<<dim3(M / 128, kHD / 128), 256, 0, stream>>>(tsnb, kD, tsnb, kD, kD,
      wvT, M, kHD, kD, kD, wv_b, nullptr, nullptr, nullptr, vTb, 1);
  // r = silu(mx @ wr + b) -> bf16 row-major
  gemm_bt<<<dim3(M / 128, kHD / 128), 256, 0, stream>>>(mx, kD, mx, kD, kD,
      wrT, M, kHD, kD, kD, wr_b, nullptr, nullptr, nullptr, rb, 2);
  // attention + gating (R6 structure)
  attn_kernel<<<dim3(1024), 256, 0, stream>>>(qb, kb, vTb, rb, aG);
  // out = [mx | aG] @ [wh1;wh2]^T_cat + wh1_b + x : split-K 2-way.
  // part0 (K 0..3071) -> Pw0 (+bias+x) ; part1 (K 3072..6143) -> Pw1.
  // 1024 blocks co-resident at 4/CU (vs 2/CU unsplit).
  gemm_bt<<<dim3(M / 128, kD / 128, 2), 256, 0, stream>>>(mx, kD, aG, kHD, kD,
      whcT, M, kD, 6144, 3072, wh1_b, x, Pw0, Pw1, nullptr, 4);
  // out = Pw0 + Pw1
  add_kernel<<<dim3(M * kD / 1024), 256, 0, stream>>>(Pw0, Pw1, out);
  (void)in_sizes; (void)n_in; (void)out_size; (void)ws_size;
}

// Round 10
// 872.441 us; speedup vs baseline: 1.1976x; 1.1976x over previous
//
#include <hip/hip_runtime.h>
#include <stdint.h>

// ---------------------------------------------------------------------------
// MovingAverageGatedAttention (MEGA-style) forward, MI355X/gfx950.
// B=2 S=2048 D=2048 Z=512 HD=4096 H=8 N=8 ZH=64 VH=512 GROUPS=32
// Pipeline: tsn -> cema -> rms(mx) -> {z->q,k ; v=silu(tsn@wv) ; r=silu(mx@wr)}
//           -> flash attn (causal, dqk=64, dv=512) * r -> [mx|attn]@[wh1;wh2]+x
// R1: cema chunked parallel scan. R2: attn vsplit+swizzle (259us).
// R3/R4: barrier-free attn regressed (spills). Reverted.
// R5: 1 barrier/iter attn (dbuf sP/sAl) + early V-to-regs: attn 198us.
// R6: attn K-LDS prefetch + speculative-exp softmax + setprio: attn <176us.
// R7: GEMM 2-phase dbuf + wh1/wh2 K-concat fusion: 985us (best).
// R8/R9/R10: three GEMM-inner-loop/grid experiments (counted vmcnt, XCD
//     swizzles, 3-buf, split-K) all neutral-to-regressive. Lesson: R7's
//     compiler-scheduled 2-phase loop is the local optimum; single-GEMM
//     dispatches simply can't fill the machine (MfmaUtil ~20%, Occ ~22%).
// R11: revert to R7-exact everywhere + fuse the three INDEPENDENT GEMMs
//     (wv, wr, wz — disjoint inputs/outputs) into ONE 2176-block dispatch
//     (flat grid, per-block decode). 8.5 blocks/CU: one GEMM's stage
//     latency hides under another's MFMA; wz's 0.5-blocks/CU tail vanishes.
// ---------------------------------------------------------------------------

typedef __bf16 bf16_t;
typedef bf16_t bf16x8 __attribute__((ext_vector_type(8)));
typedef float floatx4 __attribute__((ext_vector_type(4)));
typedef __attribute__((address_space(1))) unsigned int as1_uint;
typedef __attribute__((address_space(3))) unsigned int as3_uint;

static constexpr int kB = 2, kS = 2048, kD = 2048;
static constexpr int kZ = 512, kHD = 4096, kH = 8;
static constexpr int kG = 32;
static constexpr int kC = 64, kL = 32;  // cema: chunks, chunk length (kC*kL==kS)

__device__ __forceinline__ void async16(void* lds, const void* g) {
  // gfx950 direct global->LDS, 16B/lane. LDS dest = wave-uniform base + lane*16.
  __builtin_amdgcn_global_load_lds((const as1_uint*)(size_t)g, (as3_uint*)lds, 16, 0, 0);
}

__device__ __forceinline__ float sigm(float x) { return 1.0f / (1.0f + expf(-x)); }

// ---------------- weight fp32 (K,N) -> bf16 (N,K) transpose ----------------
// Writes Wt[n][colOff + k] with row stride ldWt (supports K-concatenation).
__global__ __launch_bounds__(256) void wtrans_kernel(const float* __restrict__ W,
                                                     bf16_t* __restrict__ Wt,
                                                     int K, int N, int ldWt,
                                                     int colOff) {
  __shared__ float tile[32][33];
  int n0 = blockIdx.x * 32, k0 = blockIdx.y * 32;
  int tx = threadIdx.x & 31, ty = threadIdx.x >> 5;  // ty in 0..7
#pragma unroll
  for (int i = 0; i < 32; i += 8)
    tile[ty + i][tx] = W[(size_t)(k0 + ty + i) * N + n0 + tx];
  __syncthreads();
#pragma unroll
  for (int i = 0; i < 32; i += 8)
    Wt[(size_t)(n0 + ty + i) * ldWt + colOff + k0 + tx] = (bf16_t)tile[tx][ty + i];
}

// ---------------- timestep norm: per-(b,s) group sums ----------------------
__global__ __launch_bounds__(256) void tsn_sums(const float* __restrict__ x,
                                                float* __restrict__ g1,
                                                float* __restrict__ g2) {
  int bs = blockIdx.x, t = threadIdx.x;
  const float4* rp = (const float4*)(x + (size_t)bs * kD + t * 8);
  float4 a = rp[0], b = rp[1];
  float s1 = a.x + a.y + a.z + a.w + b.x + b.y + b.z + b.w;
  float s2 = a.x * a.x + a.y * a.y + a.z * a.z + a.w * a.w +
             b.x * b.x + b.y * b.y + b.z * b.z + b.w * b.w;
  s1 += __shfl_xor(s1, 1); s2 += __shfl_xor(s2, 1);
  s1 += __shfl_xor(s1, 2); s2 += __shfl_xor(s2, 2);
  s1 += __shfl_xor(s1, 4); s2 += __shfl_xor(s2, 4);
  if ((t & 7) == 0) {
    int g = t >> 3, b_ = bs >> 11, s = bs & 2047;
    size_t idx = ((size_t)b_ * kG + g) * kS + s;   // [b][g][s] layout (scan-friendly)
    g1[idx] = s1; g2[idx] = s2;
  }
}

// ---------------- cumulative sum over s per (b,g) --------------------------
__global__ void tsn_scan(float* __restrict__ g1, float* __restrict__ g2) {
  int lane = threadIdx.x;  // 64 threads = 1 wave; blockIdx.x = b*32+g
  size_t base = (size_t)blockIdx.x * kS;
  float c1 = 0.f, c2 = 0.f;
  for (int c = 0; c < kS / 64; ++c) {
    size_t idx = base + c * 64 + lane;
    float v1 = g1[idx], v2 = g2[idx];
#pragma unroll
    for (int off = 1; off < 64; off <<= 1) {
      float t1 = __shfl_up(v1, off), t2 = __shfl_up(v2, off);
      if (lane >= off) { v1 += t1; v2 += t2; }
    }
    v1 += c1; v2 += c2;
    g1[idx] = v1; g2[idx] = v2;
    c1 = __shfl(v1, 63); c2 = __shfl(v2, 63);
  }
}

// ---------------- timestep norm apply (writes fp32 + bf16) -----------------
__global__ __launch_bounds__(256) void tsn_norm(const float* __restrict__ x,
    const float* __restrict__ g1, const float* __restrict__ g2,
    const float* __restrict__ w, const float* __restrict__ bias,
    float* __restrict__ tsn, bf16_t* __restrict__ tsnb) {
  int bs = blockIdx.x, t = threadIdx.x;
  int b = bs >> 11, s = bs & 2047, g = t >> 3;
  float cnt = (float)(s + 1) * 64.0f;
  size_t gidx = ((size_t)b * kG + g) * kS + s;
  float mean = g1[gidx] / cnt;
  float inv = rsqrtf(g2[gidx] / cnt - mean * mean + 1e-5f);
  size_t base = (size_t)bs * kD + t * 8;
  float4 a = ((const float4*)(x + base))[0];
  float4 c = ((const float4*)(x + base))[1];
  float v[8] = {a.x, a.y, a.z, a.w, c.x, c.y, c.z, c.w};
  float4 w0 = ((const float4*)(w + t * 8))[0], w1 = ((const float4*)(w + t * 8))[1];
  float4 b0 = ((const float4*)(bias + t * 8))[0], b1 = ((const float4*)(bias + t * 8))[1];
  float wv[8] = {w0.x, w0.y, w0.z, w0.w, w1.x, w1.y, w1.z, w1.w};
  float bv[8] = {b0.x, b0.y, b0.z, b0.w, b1.x, b1.y, b1.z, b1.w};
  float r[8];
  bf16x8 ob;
#pragma unroll
  for (int i = 0; i < 8; ++i) {
    r[i] = (v[i] - mean) * inv * wv[i] + bv[i];
    ob[i] = (bf16_t)r[i];
  }
  ((float4*)(tsn + base))[0] = make_float4(r[0], r[1], r[2], r[3]);
  ((float4*)(tsn + base))[1] = make_float4(r[4], r[5], r[6], r[7]);
  *(bf16x8*)(tsnb + base) = ob;
}

// ---------------- complex EMA, chunked parallel scan -----------------------
__device__ __forceinline__ void cema_coeffs(const float* __restrict__ alpha,
    const float* __restrict__ delta, float st, int d,
    float (&qr)[8], float (&qi)[8], float (&ur)[8], float (&ui)[8]) {
  const float4* ap = (const float4*)(alpha + (size_t)d * 8);
  const float4* dp = (const float4*)(delta + (size_t)d * 8);
  float4 a0 = ap[0], a1 = ap[1], d0 = dp[0], d1 = dp[1];
  float av[8] = {a0.x, a0.y, a0.z, a0.w, a1.x, a1.y, a1.z, a1.w};
  float dv[8] = {d0.x, d0.y, d0.z, d0.w, d1.x, d1.y, d1.z, d1.w};
#pragma unroll
  for (int n = 0; n < 8; ++n) {
    float p = sigm(av[n]);
    float qm = 1.0f - p * sigm(dv[n]);
    float ph = st * (0.78539816339744831f * (float)(n + 1));  // 2*pi*(n+1)/8
    float cs = cosf(ph), sn = sinf(ph);
    qr[n] = qm * cs; qi[n] = qm * sn;
    ur[n] = p * cs;  ui[n] = p * sn;
  }
}

__global__ __launch_bounds__(256) void cema_pass1(const float* __restrict__ tsn,
    const float* __restrict__ alpha, const float* __restrict__ delta,
    const float* __restrict__ theta, float2* __restrict__ hend) {
  int b = blockIdx.x >> 6, c = blockIdx.x & 63;
  int d = blockIdx.y * 256 + threadIdx.x;
  float st = sigm(theta[d]);
  float qr[8], qi[8], ur[8], ui[8];
  cema_coeffs(alpha, delta, st, d, qr, qi, ur, ui);
  float hr[8] = {0}, hi[8] = {0};
  const float* xp = tsn + ((size_t)b * kS + c * kL) * kD + d;
  for (int i = 0; i < kL; ++i) {
    float xt = xp[(size_t)i * kD];
#pragma unroll
    for (int n = 0; n < 8; ++n) {
      float tr = fmaf(qr[n], hr[n], fmaf(-qi[n], hi[n], ur[n] * xt));
      float ti = fmaf(qi[n], hr[n], fmaf(qr[n], hi[n], ui[n] * xt));
      hr[n] = tr; hi[n] = ti;
    }
  }
  float2* op = hend + (((size_t)(b * kC + c)) * kD + d) * 8;
#pragma unroll
  for (int n = 0; n < 8; ++n) op[n] = make_float2(hr[n], hi[n]);
}

__global__ __launch_bounds__(256) void cema_pass2(const float2* __restrict__ hend,
    const float* __restrict__ alpha, const float* __restrict__ delta,
    const float* __restrict__ theta, float2* __restrict__ hinit) {
  int tid = blockIdx.x * 256 + threadIdx.x;  // b*D*8 + d*8 + n
  int n = tid & 7, d = (tid >> 3) & 2047, b = tid >> 14;
  int dn = d * 8 + n;
  float p = sigm(alpha[dn]);
  float qm = 1.0f - p * sigm(delta[dn]);
  float ph = sigm(theta[d]) * (0.78539816339744831f * (float)(n + 1));
  float ar = qm * cosf(ph), ai = qm * sinf(ph);
#pragma unroll
  for (int t = 0; t < 5; ++t) {
    float nr = ar * ar - ai * ai;
    ai = 2.0f * ar * ai;
    ar = nr;
  }
  float hr = 0.f, hi = 0.f;
  for (int c = 0; c < kC; ++c) {
    size_t idx = (((size_t)(b * kC + c)) * kD + d) * 8 + n;
    hinit[idx] = make_float2(hr, hi);
    float2 e = hend[idx];
    float nr = fmaf(ar, hr, fmaf(-ai, hi, e.x));
    float ni = fmaf(ai, hr, fmaf(ar, hi, e.y));
    hr = nr; hi = ni;
  }
}

__global__ __launch_bounds__(256) void cema_pass3(const float* __restrict__ tsn,
    const float* __restrict__ alpha, const float* __restrict__ delta,
    const float* __restrict__ theta, const float* __restrict__ gamma,
    const float* __restrict__ omega, const float2* __restrict__ hinit,
    float* __restrict__ outc) {
  int b = blockIdx.x >> 6, c = blockIdx.x & 63;
  int d = blockIdx.y * 256 + threadIdx.x;
  float st = sigm(theta[d]);
  float qr[8], qi[8], ur[8], ui[8];
  cema_coeffs(alpha, delta, st, d, qr, qi, ur, ui);
  float gr[8], gi[8];
  const float4* gp = (const float4*)(gamma + (size_t)d * 16);
#pragma unroll
  for (int m = 0; m < 4; ++m) {
    float4 g = gp[m];
    gr[m * 2] = g.x; gi[m * 2] = g.y; gr[m * 2 + 1] = g.z; gi[m * 2 + 1] = g.w;
  }
  float om = omega[d];
  float hr[8], hi[8];
  const float2* ip = hinit + (((size_t)(b * kC + c)) * kD + d) * 8;
#pragma unroll
  for (int n = 0; n < 8; ++n) { float2 h = ip[n]; hr[n] = h.x; hi[n] = h.y; }
  const float* xp = tsn + ((size_t)b * kS + c * kL) * kD + d;
  float* op = outc + ((size_t)b * kS + c * kL) * kD + d;
  for (int i = 0; i < kL; ++i) {
    float xt = xp[(size_t)i * kD];
    float y = 0.f;
#pragma unroll
    for (int n = 0; n < 8; ++n) {
      float tr = fmaf(qr[n], hr[n], fmaf(-qi[n], hi[n], ur[n] * xt));
      float ti = fmaf(qi[n], hr[n], fmaf(qr[n], hi[n], ui[n] * xt));
      hr[n] = tr; hi[n] = ti;
      y = fmaf(tr, gr[n], fmaf(ti, gi[n], y));
    }
    op[(size_t)i * kD] = fmaf(xt, om, y);
  }
}

// ---------------- rmsnorm over D -> bf16 mx --------------------------------
__global__ __launch_bounds__(256) void rms_kernel(const float* __restrict__ in,
                                                  const float* __restrict__ w,
                                                  bf16_t* __restrict__ outb) {
  int bs = blockIdx.x, t = threadIdx.x;
  size_t base = (size_t)bs * kD + t * 8;
  float4 a = ((const float4*)(in + base))[0];
  float4 c = ((const float4*)(in + base))[1];
  float v[8] = {a.x, a.y, a.z, a.w, c.x, c.y, c.z, c.w};
  float ss = 0.f;
#pragma unroll
  for (int i = 0; i < 8; ++i) ss += v[i] * v[i];
#pragma unroll
  for (int off = 1; off < 64; off <<= 1) ss += __shfl_xor(ss, off);
  __shared__ float red[4];
  if ((t & 63) == 0) red[t >> 6] = ss;
  __syncthreads();
  ss = red[0] + red[1] + red[2] + red[3];
  float inv = rsqrtf(ss * (1.0f / 2048.0f) + 1e-5f);
  float4 w0 = ((const float4*)(w + t * 8))[0], w1 = ((const float4*)(w + t * 8))[1];
  float wv[8] = {w0.x, w0.y, w0.z, w0.w, w1.x, w1.y, w1.z, w1.w};
  bf16x8 ob;
#pragma unroll
  for (int i = 0; i < 8; ++i) ob[i] = (bf16_t)(v[i] * inv * wv[i]);
  *(bf16x8*)(outb + base) = ob;
}

// ---------------- z -> per-head rms -> gamma/beta -> rotary -> q,k bf16 ----
// q,k layout: [B][H][S][64]
__global__ __launch_bounds__(256) void zpost_kernel(const float* __restrict__ z,
    const float* __restrict__ ag, const float* __restrict__ ab,
    const float* __restrict__ freqs, bf16_t* __restrict__ q, bf16_t* __restrict__ k) {
  int bs = blockIdx.x, t = threadIdx.x;
  int b = bs >> 11, s = bs & 2047;
  int h = t >> 5, i = t & 31;  // head, rotary pair
  const float* zr = z + (size_t)bs * kZ + h * 64;
  float re = zr[2 * i], im = zr[2 * i + 1];
  float ss = re * re + im * im;
#pragma unroll
  for (int off = 1; off < 32; off <<= 1) ss += __shfl_xor(ss, off);
  float inv = rsqrtf(ss * (1.0f / 64.0f) + 1e-5f);
  float zne = re * inv, zno = im * inv;
  const float rs = 0.125f;  // 1/sqrt(64)
  int ze = h * 64 + 2 * i, zo = ze + 1;
  float qe = zne * ((ag[ze] + 1.f) * rs) + ab[ze];
  float qo = zno * ((ag[zo] + 1.f) * rs) + ab[zo];
  float ke = zne * ((ag[kZ + ze] + 1.f) * rs) + ab[kZ + ze];
  float ko = zno * ((ag[kZ + zo] + 1.f) * rs) + ab[kZ + zo];
  float cs = freqs[((size_t)s * 32 + i) * 2 + 0];
  float sn = freqs[((size_t)s * 32 + i) * 2 + 1];
  size_t o = (((size_t)b * kH + h) * kS + s) * 64 + 2 * i;
  q[o]     = (bf16_t)(qe * cs - qo * sn);
  q[o + 1] = (bf16_t)(qe * sn + qo * cs);
  k[o]     = (bf16_t)(ke * cs - ko * sn);
  k[o + 1] = (bf16_t)(ke * sn + ko * cs);
}

// ---------------- fused wv+wr+wz GEMM (R11) --------------------------------
// One dispatch, 2176 blocks: [0,1024)=wv, [1024,2048)=wr, [2048,2176)=wz.
// All K=2048, 128x128 tile, R7-exact 2-phase dbuf loop (one __syncthreads
// per K-step, STAGE(t+1) before ds_read/MFMA of t). m-fastest block decode.
// wv: A=tsnb, B=wvT, epi silu->vT[b][hd][s]. wr: A=mx, B=wrT, epi silu->rb.
// wz: A=mx, B=wzT, epi +bias->zbuf f32.
__global__ __launch_bounds__(256) void gemm_fused3(
    const bf16_t* __restrict__ tsnb, const bf16_t* __restrict__ mx,
    const bf16_t* __restrict__ wvT, const bf16_t* __restrict__ wrT,
    const bf16_t* __restrict__ wzT, const float* __restrict__ wv_b,
    const float* __restrict__ wr_b, const float* __restrict__ wz_b,
    bf16_t* __restrict__ vTb, bf16_t* __restrict__ rb,
    float* __restrict__ zbuf) {
  __shared__ __align__(16) bf16_t sA[2][128 * 32];
  __shared__ __align__(16) bf16_t sB[2][128 * 32];
  const int bid = blockIdx.x;
  const bf16_t* A; const bf16_t* Bt; const float* bias;
  int N, epi, sub;
  if (bid < 1024)      { sub = bid;        A = tsnb; Bt = wvT; bias = wv_b; N = kHD; epi = 1; }
  else if (bid < 2048) { sub = bid - 1024; A = mx;   Bt = wrT; bias = wr_b; N = kHD; epi = 2; }
  else                 { sub = bid - 2048; A = mx;   Bt = wzT; bias = wz_b; N = kZ;  epi = 0; }
  const int m0 = (sub & 31) * 128, n0 = (sub >> 5) * 128;  // mblocks==32
  const int t = threadIdx.x;
  const int wave = t >> 6, lane = t & 63;
  const int quad = lane >> 4, l16 = lane & 15;
  const int wm = (wave >> 1) * 64, wn = (wave & 1) * 64;
  const int K = kD;

  floatx4 acc[4][4];
#pragma unroll
  for (int i = 0; i < 4; ++i)
#pragma unroll
    for (int j = 0; j < 4; ++j) acc[i][j] = (floatx4){0.f, 0.f, 0.f, 0.f};

  const int seg0 = wave * 64 + lane;
  const int seg1 = 256 + wave * 64 + lane;
  const int r0 = seg0 >> 2, c0 = (seg0 & 3) * 8;
  const int r1 = seg1 >> 2, c1 = (seg1 & 3) * 8;

  auto stage = [&](int buf, int kt) {
    async16(sA[buf] + (size_t)(wave * 64) * 8,       A + (size_t)(m0 + r0) * K + kt + c0);
    async16(sA[buf] + (size_t)(256 + wave * 64) * 8, A + (size_t)(m0 + r1) * K + kt + c1);
    async16(sB[buf] + (size_t)(wave * 64) * 8,       Bt + (size_t)(n0 + r0) * K + kt + c0);
    async16(sB[buf] + (size_t)(256 + wave * 64) * 8, Bt + (size_t)(n0 + r1) * K + kt + c1);
  };

  stage(0, 0);
  __syncthreads();

  const int nsteps = K >> 5;
  for (int st = 0; st < nsteps; ++st) {
    const int cur = st & 1;
    if (st + 1 < nsteps) stage(cur ^ 1, (st + 1) << 5);

    bf16x8 af[4], bfr[4];
#pragma unroll
    for (int i = 0; i < 4; ++i)
      af[i] = *(const bf16x8*)(sA[cur] + (wm + i * 16 + l16) * 32 + quad * 8);
#pragma unroll
    for (int j = 0; j < 4; ++j)
      bfr[j] = *(const bf16x8*)(sB[cur] + (wn + j * 16 + l16) * 32 + quad * 8);
#pragma unroll
    for (int i = 0; i < 4; ++i)
#pragma unroll
      for (int j = 0; j < 4; ++j)
        acc[i][j] = __builtin_amdgcn_mfma_f32_16x16x32_bf16(af[i], bfr[j], acc[i][j], 0, 0, 0);

    __syncthreads();
  }

#pragma unroll
  for (int i = 0; i < 4; ++i) {
#pragma unroll
    for (int j = 0; j < 4; ++j) {
#pragma unroll
      for (int r = 0; r < 4; ++r) {
        int row = m0 + wm + i * 16 + quad * 4 + r;
        int col = n0 + wn + j * 16 + l16;
        size_t idx = (size_t)row * N + col;
        float v = acc[i][j][r];
        if (epi == 0) {
          zbuf[idx] = v + bias[col];
        } else if (epi == 1) {
          v += bias[col];
          v = v / (1.f + __expf(-v));
          // vT[b][hd][s] : hd = col, b = row>>11, s = row&2047
          size_t vidx = ((size_t)(row >> 11) * kHD + col) * (size_t)kS + (row & 2047);
          vTb[vidx] = (bf16_t)v;
        } else {
          v += bias[col];
          v = v / (1.f + __expf(-v));
          rb[idx] = (bf16_t)v;
        }
      }
    }
  }
}

// ---------------- bf16 MFMA GEMM (whc): C = [A1|A2] @ Bt^T -----------------
// R7-exact: 128x128 tile, BK=32, double-buffered sA/sB, ONE __syncthreads
// per K-step; STAGE(t+1) issued before ds_read/MFMA of tile t.
// A source switches from (A1,lda1) to (A2,lda2) at column K1.
// epi 3: out = acc + bias + add1 (f32).
__global__ __launch_bounds__(256) void gemm_bt(const bf16_t* __restrict__ A1,
    int lda1, const bf16_t* __restrict__ A2, int lda2, int K1,
    const bf16_t* __restrict__ Bt, int M, int N, int K,
    const float* __restrict__ bias, const float* __restrict__ add1,
    float* __restrict__ outF) {
  __shared__ __align__(16) bf16_t sA[2][128 * 32];
  __shared__ __align__(16) bf16_t sB[2][128 * 32];
  const int t = threadIdx.x;
  const int wave = t >> 6, lane = t & 63;
  const int quad = lane >> 4, l16 = lane & 15;
  const int m0 = blockIdx.x * 128, n0 = blockIdx.y * 128;
  const int wm = (wave >> 1) * 64, wn = (wave & 1) * 64;

  floatx4 acc[4][4];
#pragma unroll
  for (int i = 0; i < 4; ++i)
#pragma unroll
    for (int j = 0; j < 4; ++j) acc[i][j] = (floatx4){0.f, 0.f, 0.f, 0.f};

  const int seg0 = wave * 64 + lane;
  const int seg1 = 256 + wave * 64 + lane;
  const int r0 = seg0 >> 2, c0 = (seg0 & 3) * 8;
  const int r1 = seg1 >> 2, c1 = (seg1 & 3) * 8;

  auto stage = [&](int buf, int kt) {
    const bf16_t* Ab; int ldab; int kk;
    if (kt < K1) { Ab = A1; ldab = lda1; kk = kt; }
    else         { Ab = A2; ldab = lda2; kk = kt - K1; }
    async16(sA[buf] + (size_t)(wave * 64) * 8,       Ab + (size_t)(m0 + r0) * ldab + kk + c0);
    async16(sA[buf] + (size_t)(256 + wave * 64) * 8, Ab + (size_t)(m0 + r1) * ldab + kk + c1);
    async16(sB[buf] + (size_t)(wave * 64) * 8,       Bt + (size_t)(n0 + r0) * K + kt + c0);
    async16(sB[buf] + (size_t)(256 + wave * 64) * 8, Bt + (size_t)(n0 + r1) * K + kt + c1);
  };

  stage(0, 0);
  __syncthreads();

  const int nsteps = K >> 5;
  for (int st = 0; st < nsteps; ++st) {
    const int cur = st & 1;
    if (st + 1 < nsteps) stage(cur ^ 1, (st + 1) << 5);

    bf16x8 af[4], bfr[4];
#pragma unroll
    for (int i = 0; i < 4; ++i)
      af[i] = *(const bf16x8*)(sA[cur] + (wm + i * 16 + l16) * 32 + quad * 8);
#pragma unroll
    for (int j = 0; j < 4; ++j)
      bfr[j] = *(const bf16x8*)(sB[cur] + (wn + j * 16 + l16) * 32 + quad * 8);
#pragma unroll
    for (int i = 0; i < 4; ++i)
#pragma unroll
      for (int j = 0; j < 4; ++j)
        acc[i][j] = __builtin_amdgcn_mfma_f32_16x16x32_bf16(af[i], bfr[j], acc[i][j], 0, 0, 0);

    __syncthreads();
  }

#pragma unroll
  for (int i = 0; i < 4; ++i) {
#pragma unroll
    for (int j = 0; j < 4; ++j) {
#pragma unroll
      for (int r = 0; r < 4; ++r) {
        int row = m0 + wm + i * 16 + quad * 4 + r;
        int col = n0 + wn + j * 16 + l16;
        size_t idx = (size_t)row * N + col;
        outF[idx] = acc[i][j][r] + bias[col] + add1[idx];
      }
    }
  }
}

// ---------------- flash attention (causal) + r-gating ----------------------
// R6 structure (verified). flat grid 1024 = 32 qt-levels (desc) x 16 bh x 2 vs.
// ONE barrier per kt-iteration; sP/sAl dbuf; K tiles dbuf in LDS via
// pre-swizzled global_load_lds; speculative-exp softmax; setprio on PV.
__global__ __launch_bounds__(256) void attn_kernel(const bf16_t* __restrict__ qg,
    const bf16_t* __restrict__ kg, const bf16_t* __restrict__ vT,
    const bf16_t* __restrict__ rg, bf16_t* __restrict__ attnG) {
  const int bid = blockIdx.x;
  const int qt = (kS / 64 - 1) - (bid >> 5);  // longest-first dispatch
  const int bh = (bid >> 1) & 15;
  const int vs = bid & 1;
  const int b = bh >> 3, h = bh & 7;
  const int t = threadIdx.x;
  const int w = t >> 6, lane = t & 63;
  const int quad = lane >> 4, l16 = lane & 15;
  const int q0 = qt * 64;

  __shared__ __align__(16) bf16_t sP[2][64 * 64];  // double-buffered P
  __shared__ __align__(16) bf16_t sK[2][64 * 64];  // double-buffered K tiles
  __shared__ float sM[64], sL[64], sAl[2][64];     // m/l + dbuf rescale
  if (t < 64) { sM[t] = 0.f; sL[t] = 0.f; }        // m init 0 (scores ~|1|)

  const bf16_t* qbase = qg + ((size_t)bh * kS + q0) * 64;
  const bf16_t* kbase = kg + (size_t)bh * kS * 64;
  const bf16_t* vbase = vT + ((size_t)bh * 512 + vs * 256 + w * 64) * kS;

  // stage K tile [k0..k0+63][0..63] into dstbuf, source pre-swizzled so that
  // LDS[row*64 + cc*8 ..] holds K[row][ (cc^(row&7))*8 .. ] (cc = 16B chunk).
  auto stage_k = [&](bf16_t* dstbuf, int k0) {
#pragma unroll
    for (int half = 0; half < 2; ++half) {
      int seg = half * 256 + w * 64 + lane;   // 0..511, 16B each
      int r = seg >> 3, cc = seg & 7;
      async16(dstbuf + (size_t)(half * 256 + w * 64) * 8,
              kbase + (size_t)(k0 + r) * 64 + (cc ^ (r & 7)) * 8);
    }
  };

  bf16x8 qfrag[2];
#pragma unroll
  for (int ks = 0; ks < 2; ++ks)
    qfrag[ks] = *(const bf16x8*)(qbase + (size_t)(w * 16 + l16) * 64 + ks * 32 + quad * 8);

  floatx4 oacc[4][4];  // [mi(16 q-rows)][nj(16 v-dims)]
#pragma unroll
  for (int i = 0; i < 4; ++i)
#pragma unroll
    for (int j = 0; j < 4; ++j) oacc[i][j] = (floatx4){0.f, 0.f, 0.f, 0.f};

  stage_k(sK[0], 0);   // prologue: K tile 0
  __syncthreads();     // drains vmcnt (K0 + qfrag) ; publishes sM/sL init

  for (int kt = 0; kt <= qt; ++kt) {
    const int k0 = kt * 64;
    const int pb = kt & 1;

    if (kt < qt) stage_k(sK[pb ^ 1], k0 + 64);  // prefetch next K tile

    // ---- early V issue: this wave's 64 v-dims for tile kt (to registers).
    bf16x8 vf[2][4];
#pragma unroll
    for (int ks = 0; ks < 2; ++ks)
#pragma unroll
      for (int nj = 0; nj < 4; ++nj)
        vf[ks][nj] = *(const bf16x8*)(vbase + (size_t)(nj * 16 + l16) * kS + k0 + ks * 32 + quad * 8);

    // ---- QK^T for this wave's 16 q-rows, K from swizzled LDS -------------
    floatx4 sacc[4];
#pragma unroll
    for (int nt = 0; nt < 4; ++nt) sacc[nt] = (floatx4){0.f, 0.f, 0.f, 0.f};
#pragma unroll
    for (int ks = 0; ks < 2; ++ks)
#pragma unroll
      for (int nt = 0; nt < 4; ++nt) {
        int row = nt * 16 + l16;
        int ch = (ks * 4 + quad) ^ (row & 7);
        bf16x8 kf = *(const bf16x8*)(sK[pb] + row * 64 + ch * 8);
        sacc[nt] = __builtin_amdgcn_mfma_f32_16x16x32_bf16(qfrag[ks], kf, sacc[nt], 0, 0, 0);
      }
    if (kt == qt) {  // causal mask on diagonal tile
#pragma unroll
      for (int nt = 0; nt < 4; ++nt)
#pragma unroll
        for (int r = 0; r < 4; ++r) {
          int sk = k0 + nt * 16 + l16;
          int qq = q0 + w * 16 + quad * 4 + r;
          if (sk > qq) sacc[nt][r] = -1e30f;
        }
    }

    // ---- speculative-exp online softmax ---------------------------------
    float mo[4], mloc[4], lspec[4];
#pragma unroll
    for (int r = 0; r < 4; ++r) {
      mo[r] = sM[w * 16 + quad * 4 + r];  // same-wave owned
      mloc[r] = fmaxf(fmaxf(sacc[0][r], sacc[1][r]), fmaxf(sacc[2][r], sacc[3][r]));
    }
#pragma unroll
    for (int r = 0; r < 4; ++r) {
      float s = 0.f;
#pragma unroll
      for (int nt = 0; nt < 4; ++nt) {
        float e = __expf(sacc[nt][r] - mo[r]);
        sacc[nt][r] = e;
        s += e;
      }
      lspec[r] = s;
    }
#pragma unroll
    for (int off = 1; off < 16; off <<= 1)
#pragma unroll
      for (int r = 0; r < 4; ++r) {
        mloc[r] = fmaxf(mloc[r], __shfl_xor(mloc[r], off));
        lspec[r] += __shfl_xor(lspec[r], off);
      }
    float mnew[4], al[4];
#pragma unroll
    for (int r = 0; r < 4; ++r) {
      mnew[r] = fmaxf(mo[r], mloc[r]);
      al[r] = __expf(mo[r] - mnew[r]);
    }
    if (l16 == 0) {
#pragma unroll
      for (int r = 0; r < 4; ++r) {
        int row = w * 16 + quad * 4 + r;
        sM[row] = mnew[r];
        sL[row] = al[r] * (sL[row] + lspec[r]);
        sAl[pb][row] = al[r];
      }
    }
#pragma unroll
    for (int nt = 0; nt < 4; ++nt)
#pragma unroll
      for (int r = 0; r < 4; ++r) {
        int row = w * 16 + quad * 4 + r;
        sP[pb][row * 64 + ((nt * 16 + l16) ^ ((row & 7) << 3))] = (bf16_t)(sacc[nt][r] * al[r]);
      }

    __syncthreads();  // single barrier: P/sAl visible; vf + K-prefetch drained

    // ---- rescale O then accumulate P @ V (vf already in registers) ------
#pragma unroll
    for (int mi = 0; mi < 4; ++mi)
#pragma unroll
      for (int r = 0; r < 4; ++r) {
        float a = sAl[pb][mi * 16 + quad * 4 + r];
#pragma unroll
        for (int nj = 0; nj < 4; ++nj) oacc[mi][nj][r] *= a;
      }
    __builtin_amdgcn_s_setprio(1);
#pragma unroll
    for (int ks = 0; ks < 2; ++ks) {
      bf16x8 pa[4];
#pragma unroll
      for (int mi = 0; mi < 4; ++mi) {
        int row = mi * 16 + l16;
        pa[mi] = *(const bf16x8*)(sP[pb] + row * 64 + ((ks * 32 + quad * 8) ^ ((row & 7) << 3)));
      }
#pragma unroll
      for (int nj = 0; nj < 4; ++nj)
#pragma unroll
        for (int mi = 0; mi < 4; ++mi)
          oacc[mi][nj] = __builtin_amdgcn_mfma_f32_16x16x32_bf16(pa[mi], vf[ks][nj], oacc[mi][nj], 0, 0, 0);
    }
    __builtin_amdgcn_s_setprio(0);
  }

  // epilogue: O/l * r -> attnG bf16
#pragma unroll
  for (int mi = 0; mi < 4; ++mi)
#pragma unroll
    for (int r = 0; r < 4; ++r) {
      int srow = q0 + mi * 16 + quad * 4 + r;
      float linv = 1.0f / sL[mi * 16 + quad * 4 + r];
#pragma unroll
      for (int nj = 0; nj < 4; ++nj) {
        int hd = h * 512 + vs * 256 + w * 64 + nj * 16 + l16;
        size_t idx = ((size_t)b * kS + srow) * kHD + hd;
        float rv = (float)rg[idx];
        attnG[idx] = (bf16_t)(oacc[mi][nj][r] * linv * rv);
      }
    }
}

// ---------------------------------------------------------------------------
extern "C" void kernel_launch(void* const* d_in, const int* in_sizes, int n_in,
                              void* d_out, int out_size, void* d_ws, size_t ws_size,
                              hipStream_t stream) {
  const float* x      = (const float*)d_in[0];
  const float* tnw    = (const float*)d_in[1];
  const float* tnb    = (const float*)d_in[2];
  const float* ealpha = (const float*)d_in[3];
  const float* edelta = (const float*)d_in[4];
  const float* etheta = (const float*)d_in[5];
  const float* egamma = (const float*)d_in[6];
  const float* eomega = (const float*)d_in[7];
  const float* rmsw   = (const float*)d_in[8];
  const float* wz_w   = (const float*)d_in[9];
  const float* wz_b   = (const float*)d_in[10];
  const float* wv_w   = (const float*)d_in[11];
  const float* wv_b   = (const float*)d_in[12];
  const float* wr_w   = (const float*)d_in[13];
  const float* wr_b   = (const float*)d_in[14];
  const float* wh1_w  = (const float*)d_in[15];
  const float* wh1_b  = (const float*)d_in[16];
  const float* wh2_w  = (const float*)d_in[17];
  const float* ag     = (const float*)d_in[18];
  const float* ab     = (const float*)d_in[19];
  const float* freqs  = (const float*)d_in[20];
  float* out = (float*)d_out;

  char* ws = (char*)d_ws;
  size_t off = 0;
  auto alloc = [&](size_t bytes) -> void* {
    void* p = ws + off;
    off += (bytes + 255) & ~(size_t)255;
    return p;
  };
  // buf1: tsn fp32, later reused as vT bf16 (tsn fp32 dead after cema)
  float*  tsn  = (float*)alloc(8388608ull * 4);
  bf16_t* tsnb = (bf16_t*)alloc(8388608ull * 2);
  float*  g1   = (float*)alloc(131072ull * 4);
  float*  g2   = (float*)alloc(131072ull * 4);
  // buf2: cema fp32 (dead after rms)
  float*  cema = (float*)alloc(8388608ull * 4);
  bf16_t* mx   = (bf16_t*)alloc(8388608ull * 2);
  bf16_t* wzT  = (bf16_t*)alloc(1048576ull * 2);
  bf16_t* wvT  = (bf16_t*)alloc(8388608ull * 2);
  bf16_t* wrT  = (bf16_t*)alloc(8388608ull * 2);
  bf16_t* whcT = (bf16_t*)alloc(12582912ull * 2);  // [2048][6144] = wh1|wh2 cat
  float*  zbuf = (float*)alloc(2097152ull * 4);
  bf16_t* qb   = (bf16_t*)alloc(2097152ull * 2);
  bf16_t* kb   = (bf16_t*)alloc(2097152ull * 2);
  bf16_t* rb   = (bf16_t*)alloc(16777216ull * 2);
  bf16_t* aG   = (bf16_t*)alloc(16777216ull * 2);
  bf16_t* vTb  = (bf16_t*)tsn;   // alias buf1 (16.8M bf16 fits in 33.5MB)
  float*  h1   = cema;           // alias buf2 (unused name kept for clarity)
  // cema scratch: aliases rb/aG — lifetimes disjoint (cema ends before r/attn)
  float2* hend  = (float2*)rb;   // B*C*D*N complex = 16.8 MB (rb is 33.5 MB)
  float2* hinit = (float2*)aG;   // 16.8 MB (aG is 33.5 MB)
  (void)h1;

  // weights -> bf16, transposed to (N,K); wh1/wh2 concatenated along K
  wtrans_kernel<<<dim3(kZ / 32, kD / 32), 256, 0, stream>>>(wz_w, wzT, kD, kZ, kD, 0);
  wtrans_kernel<<<dim3(kHD / 32, kD / 32), 256, 0, stream>>>(wv_w, wvT, kD, kHD, kD, 0);
  wtrans_kernel<<<dim3(kHD / 32, kD / 32), 256, 0, stream>>>(wr_w, wrT, kD, kHD, kD, 0);
  wtrans_kernel<<<dim3(kD / 32, kD / 32), 256, 0, stream>>>(wh1_w, whcT, kD, kD, 6144, 0);
  wtrans_kernel<<<dim3(kD / 32, kHD / 32), 256, 0, stream>>>(wh2_w, whcT, kHD, kD, 6144, kD);

  // timestep norm
  tsn_sums<<<kB * kS, 256, 0, stream>>>(x, g1, g2);
  tsn_scan<<<kB * kG, 64, 0, stream>>>(g1, g2);
  tsn_norm<<<kB * kS, 256, 0, stream>>>(x, g1, g2, tnw, tnb, tsn, tsnb);

  // complex EMA + residual omega (chunked parallel scan)
  cema_pass1<<<dim3(kB * kC, kD / 256), 256, 0, stream>>>(tsn, ealpha, edelta,
                                                          etheta, hend);
  cema_pass2<<<kB * kD * 8 / 256, 256, 0, stream>>>(hend, ealpha, edelta,
                                                    etheta, hinit);
  cema_pass3<<<dim3(kB * kC, kD / 256), 256, 0, stream>>>(tsn, ealpha, edelta,
      etheta, egamma, eomega, hinit, cema);
  // mx = rmsnorm(cema) -> bf16
  rms_kernel<<<kB * kS, 256, 0, stream>>>(cema, rmsw, mx);

  const int M = kB * kS;  // 4096
  // fused wv+wr+wz: 2176 blocks (1024 wv + 1024 wr + 128 wz), 8.5/CU.
  // All read-only inputs ready (mx, tsnb); outputs disjoint (vTb=tsn region
  // dead after cema; rb/zbuf fresh).
  gemm_fused3<<<dim3(2176), 256, 0, stream>>>(tsnb, mx, wvT, wrT, wzT,
      wv_b, wr_b, wz_b, vTb, rb, zbuf);
  // z -> q,k (per-head rms, gamma/beta, rotary)
  zpost_kernel<<<kB * kS, 256, 0, stream>>>(zbuf, ag, ab, freqs, qb, kb);
  // attention + gating (R6 structure)
  attn_kernel<<<dim3(1024), 256, 0, stream>>>(qb, kb, vTb, rb, aG);
  // out = [mx | aG] @ [wh1;wh2]^T_cat + wh1_b + x   (K=6144, switch at 2048)
  gemm_bt<<<dim3(M / 128, kD / 128), 256, 0, stream>>>(mx, kD, aG, kHD, kD,
      whcT, M, kD, 6144, wh1_b, x, out);
  (void)in_sizes; (void)n_in; (void)out_size; (void)ws_size;
}